// Round 1
// baseline (3035.959 us; speedup 1.0000x reference)
//
#include <hip/hip_runtime.h>

#define N_NODES 100000
#define E_EDGES 1600000
#define C 128

// ---------------------------------------------------------------------------
// Phase 1: scatter-add  acc[dst] += x[src]  and deg[dst] += 1  over COO edges.
// 32 threads per edge, each thread owns 4 contiguous channels (float4 gather).
// 204.8M f32 atomics total — expected bottleneck this round.
// ---------------------------------------------------------------------------
__global__ __launch_bounds__(256) void scatter_kernel(
    const float* __restrict__ x, const int* __restrict__ erow,
    const int* __restrict__ ecol, float* __restrict__ acc,
    float* __restrict__ deg) {
  long tid = (long)blockIdx.x * 256 + threadIdx.x;
  int e = (int)(tid >> 5);
  int lane = (int)(tid & 31);
  if (e >= E_EDGES) return;
  int src = ecol[e];
  int dst = erow[e];
  float4 v = ((const float4*)(x + (long)src * C))[lane];
  float* a = acc + (long)dst * C + lane * 4;
  atomicAdd(a + 0, v.x);
  atomicAdd(a + 1, v.y);
  atomicAdd(a + 2, v.z);
  atomicAdd(a + 3, v.w);
  if (lane == 0) atomicAdd(deg + dst, 1.0f);
}

// ---------------------------------------------------------------------------
// Phase 2: fused  out = relu( (acc @ W_l) * (1/max(deg,1)) + x @ W_r + b_l )
// (mean-normalization folded into the epilogue: (sum/deg)@W = (sum@W)/deg)
// Block = 256 threads, 32 rows/block. Thread (c = tid&127, half = tid>>7)
// computes 16 rows x 1 channel for BOTH matmuls. A/x rows staged in LDS;
// per-wave LDS reads are same-address broadcasts (conflict-free). W reads are
// coalesced 256B/wave and L1/L2-resident (64 KB each).
// ---------------------------------------------------------------------------
__global__ __launch_bounds__(256) void gemm_kernel(
    const float* __restrict__ acc, const float* __restrict__ x,
    const float* __restrict__ W_l, const float* __restrict__ b_l,
    const float* __restrict__ W_r, const float* __restrict__ deg,
    float* __restrict__ out) {
  __shared__ float lds_a[32][C];
  __shared__ float lds_x[32][C];
  int tid = threadIdx.x;
  long base_row = (long)blockIdx.x * 32;

  // Stage 32 rows of acc and x (32*128 floats each) via float4, coalesced.
  for (int i = tid; i < 32 * (C / 4); i += 256) {
    int r = i >> 5;         // 32 float4 per row
    int kq = i & 31;
    float4 va = ((const float4*)(acc + (base_row + r) * C))[kq];
    float4 vx = ((const float4*)(x + (base_row + r) * C))[kq];
    ((float4*)lds_a[r])[kq] = va;
    ((float4*)lds_x[r])[kq] = vx;
  }
  __syncthreads();

  int c = tid & 127;
  int r0 = (tid >> 7) * 16;

  float sl[16], sr[16];
#pragma unroll
  for (int r = 0; r < 16; ++r) { sl[r] = 0.0f; sr[r] = 0.0f; }

  for (int k = 0; k < C; k += 4) {
    float wl0 = W_l[(k + 0) * C + c];
    float wl1 = W_l[(k + 1) * C + c];
    float wl2 = W_l[(k + 2) * C + c];
    float wl3 = W_l[(k + 3) * C + c];
    float wr0 = W_r[(k + 0) * C + c];
    float wr1 = W_r[(k + 1) * C + c];
    float wr2 = W_r[(k + 2) * C + c];
    float wr3 = W_r[(k + 3) * C + c];
#pragma unroll
    for (int r = 0; r < 16; ++r) {
      float4 a4 = *(const float4*)&lds_a[r0 + r][k];
      float4 x4 = *(const float4*)&lds_x[r0 + r][k];
      sl[r] += a4.x * wl0 + a4.y * wl1 + a4.z * wl2 + a4.w * wl3;
      sr[r] += x4.x * wr0 + x4.y * wr1 + x4.z * wr2 + x4.w * wr3;
    }
  }

  float b = b_l[c];
#pragma unroll
  for (int r = 0; r < 16; ++r) {
    long row = base_row + r0 + r;
    float d = deg[row];
    float s = 1.0f / fmaxf(d, 1.0f);
    float o = sl[r] * s + sr[r] + b;
    out[row * C + c] = fmaxf(o, 0.0f);
  }
}

extern "C" void kernel_launch(void* const* d_in, const int* in_sizes, int n_in,
                              void* d_out, int out_size, void* d_ws, size_t ws_size,
                              hipStream_t stream) {
  const float* x   = (const float*)d_in[0];
  const int* erow  = (const int*)d_in[1];   // dst
  const int* ecol  = (const int*)d_in[2];   // src
  const float* W_l = (const float*)d_in[3];
  const float* b_l = (const float*)d_in[4];
  const float* W_r = (const float*)d_in[5];
  float* out = (float*)d_out;

  float* acc = (float*)d_ws;                      // [N, C] fp32 sums
  float* deg = acc + (long)N_NODES * C;           // [N]    fp32 degree

  // ws is re-poisoned to 0xAA before every timed call — zero it each time.
  hipMemsetAsync(d_ws, 0, ((long)N_NODES * C + N_NODES) * sizeof(float),
                 stream);

  scatter_kernel<<<(E_EDGES * 32) / 256, 256, 0, stream>>>(x, erow, ecol, acc,
                                                           deg);
  gemm_kernel<<<N_NODES / 32, 256, 0, stream>>>(acc, x, W_l, b_l, W_r, deg,
                                                out);
}

// Round 2
// 791.777 us; speedup vs baseline: 3.8344x; 3.8344x over previous
//
#include <hip/hip_runtime.h>

#define N_NODES 100000
#define E_EDGES 1600000
#define C 128

// ---------------------------------------------------------------------------
// CSR build: counting sort of edges by dst. Only 3.2M int atomics total
// (vs 205M float atomics in R1 whose write-through cost 3.25 GB at TCC).
// ---------------------------------------------------------------------------
__global__ __launch_bounds__(256) void hist_kernel(const int* __restrict__ erow,
                                                   int* __restrict__ deg) {
  int e = blockIdx.x * 256 + threadIdx.x;
  if (e < E_EDGES) atomicAdd(&deg[erow[e]], 1);
}

// Single-block exclusive scan over N=100k degree counters (800 KB traffic).
__global__ __launch_bounds__(1024) void scan_kernel(const int* __restrict__ deg,
                                                    int* __restrict__ off,
                                                    int* __restrict__ cursor) {
  __shared__ int lds[1024];
  int t = threadIdx.x;
  const int CH = (N_NODES + 1023) / 1024;  // 98
  int lo = t * CH;
  int hi = lo + CH < N_NODES ? lo + CH : N_NODES;
  int s = 0;
  for (int i = lo; i < hi; ++i) s += deg[i];
  lds[t] = s;
  __syncthreads();
  for (int d = 1; d < 1024; d <<= 1) {  // Hillis-Steele inclusive scan
    int v = 0;
    if (t >= d) v = lds[t - d];
    __syncthreads();
    if (t >= d) lds[t] += v;
    __syncthreads();
  }
  int p = (t == 0) ? 0 : lds[t - 1];  // exclusive prefix for this chunk
  for (int i = lo; i < hi; ++i) {
    off[i] = p;
    cursor[i] = p;
    p += deg[i];
  }
  if (t == 0) off[N_NODES] = E_EDGES;
}

__global__ __launch_bounds__(256) void build_kernel(
    const int* __restrict__ erow, const int* __restrict__ ecol,
    int* __restrict__ cursor, int* __restrict__ ssrc) {
  int e = blockIdx.x * 256 + threadIdx.x;
  if (e >= E_EDGES) return;
  int pos = atomicAdd(&cursor[erow[e]], 1);
  ssrc[pos] = ecol[e];
}

// ---------------------------------------------------------------------------
// Fused: per 32-node block
//   (a) gather-average neighbor rows of x via CSR into LDS (mean folded in;
//       agg never materialized in HBM),
//   (b) stage the block's own x rows,
//   (c) out = relu(agg @ W_l + x @ W_r + b_l).
// Gather: wave w handles 8 nodes; 64 lanes read one 512B x-row per edge
// (fully coalesced, L3-resident). Edge loop unrolled x2 for MLP.
// ---------------------------------------------------------------------------
__global__ __launch_bounds__(256) void fused_kernel(
    const float* __restrict__ x, const int* __restrict__ off,
    const int* __restrict__ ssrc, const float* __restrict__ W_l,
    const float* __restrict__ b_l, const float* __restrict__ W_r,
    float* __restrict__ out) {
  __shared__ float lds_a[32][C];
  __shared__ float lds_x[32][C];
  int tid = threadIdx.x;
  long base = (long)blockIdx.x * 32;

  // Stage this block's own 32 x-rows (contiguous, coalesced float4).
  for (int i = tid; i < 32 * (C / 4); i += 256) {
    int r = i >> 5;
    int kq = i & 31;
    ((float4*)lds_x[r])[kq] = ((const float4*)(x + (base + r) * C))[kq];
  }

  // Gather-average into lds_a. Lane owns channels {2*lane, 2*lane+1}.
  int wave = tid >> 6;
  int lane = tid & 63;
  for (int j = 0; j < 8; ++j) {
    int n = wave * 8 + j;
    long row = base + n;
    int e0 = off[row];       // wave-uniform -> scalar loads
    int e1 = off[row + 1];
    float sx = 0.0f, sy = 0.0f;
    int e = e0;
    for (; e + 1 < e1; e += 2) {  // 2 independent row-loads in flight
      int s0 = ssrc[e];
      int s1 = ssrc[e + 1];
      float2 v0 = ((const float2*)(x + (long)s0 * C))[lane];
      float2 v1 = ((const float2*)(x + (long)s1 * C))[lane];
      sx += v0.x + v1.x;
      sy += v0.y + v1.y;
    }
    if (e < e1) {
      int s0 = ssrc[e];
      float2 v0 = ((const float2*)(x + (long)s0 * C))[lane];
      sx += v0.x;
      sy += v0.y;
    }
    float inv = 1.0f / fmaxf((float)(e1 - e0), 1.0f);
    float2 r2 = {sx * inv, sy * inv};
    ((float2*)lds_a[n])[lane] = r2;  // 8B stride -> 2-way LDS alias (free)
  }
  __syncthreads();

  // GEMM: thread (c = tid&127, half = tid>>7) computes 16 rows x 1 channel.
  int c = tid & 127;
  int r0 = (tid >> 7) * 16;

  float sl[16], sr[16];
#pragma unroll
  for (int r = 0; r < 16; ++r) { sl[r] = 0.0f; sr[r] = 0.0f; }

  for (int k = 0; k < C; k += 4) {
    float wl0 = W_l[(k + 0) * C + c];
    float wl1 = W_l[(k + 1) * C + c];
    float wl2 = W_l[(k + 2) * C + c];
    float wl3 = W_l[(k + 3) * C + c];
    float wr0 = W_r[(k + 0) * C + c];
    float wr1 = W_r[(k + 1) * C + c];
    float wr2 = W_r[(k + 2) * C + c];
    float wr3 = W_r[(k + 3) * C + c];
#pragma unroll
    for (int r = 0; r < 16; ++r) {
      float4 a4 = *(const float4*)&lds_a[r0 + r][k];
      float4 x4 = *(const float4*)&lds_x[r0 + r][k];
      sl[r] += a4.x * wl0 + a4.y * wl1 + a4.z * wl2 + a4.w * wl3;
      sr[r] += x4.x * wr0 + x4.y * wr1 + x4.z * wr2 + x4.w * wr3;
    }
  }

  float b = b_l[c];
#pragma unroll
  for (int r = 0; r < 16; ++r) {
    long row = base + r0 + r;
    float o = sl[r] + sr[r] + b;  // mean already folded into lds_a
    out[row * C + c] = fmaxf(o, 0.0f);
  }
}

extern "C" void kernel_launch(void* const* d_in, const int* in_sizes, int n_in,
                              void* d_out, int out_size, void* d_ws, size_t ws_size,
                              hipStream_t stream) {
  const float* x   = (const float*)d_in[0];
  const int* erow  = (const int*)d_in[1];   // dst
  const int* ecol  = (const int*)d_in[2];   // src
  const float* W_l = (const float*)d_in[3];
  const float* b_l = (const float*)d_in[4];
  const float* W_r = (const float*)d_in[5];
  float* out = (float*)d_out;

  // ws layout (ints): deg[N] | off[N+1] | cursor[N] | ssrc[E]  (~7.6 MB)
  int* deg    = (int*)d_ws;
  int* off    = deg + N_NODES;
  int* cursor = off + N_NODES + 1;
  int* ssrc   = cursor + N_NODES;

  hipMemsetAsync(deg, 0, N_NODES * sizeof(int), stream);  // ws is re-poisoned

  hist_kernel<<<(E_EDGES + 255) / 256, 256, 0, stream>>>(erow, deg);
  scan_kernel<<<1, 1024, 0, stream>>>(deg, off, cursor);
  build_kernel<<<(E_EDGES + 255) / 256, 256, 0, stream>>>(erow, ecol, cursor,
                                                          ssrc);
  fused_kernel<<<N_NODES / 32, 256, 0, stream>>>(x, off, ssrc, W_l, b_l, W_r,
                                                 out);
}

// Round 4
// 389.637 us; speedup vs baseline: 7.7918x; 2.0321x over previous
//
#include <hip/hip_runtime.h>

#define N_NODES 100000
#define E_EDGES 1600000
#define C 128

typedef __attribute__((ext_vector_type(8))) short short8;   // 8 bf16 (4 VGPRs)
typedef __attribute__((ext_vector_type(4))) float f32x4;    // MFMA acc

__device__ __forceinline__ unsigned short f2bf(float f) {  // RNE fp32->bf16
  unsigned int b = __float_as_uint(f);
  return (unsigned short)((b + 0x7fffu + ((b >> 16) & 1u)) >> 16);
}
__device__ __forceinline__ float bflo(unsigned int v) {  // low bf16 -> f32
  return __uint_as_float(v << 16);
}
__device__ __forceinline__ float bfhi(unsigned int v) {  // high bf16 -> f32
  return __uint_as_float(v & 0xffff0000u);
}

// x (fp32) -> xh (bf16). 77 MB streaming pass.
__global__ __launch_bounds__(256) void cvt_kernel(const float* __restrict__ x,
                                                  ushort* __restrict__ xh) {
  int t = blockIdx.x * 256 + threadIdx.x;  // t < N*C/8
  float4 a = ((const float4*)x)[2 * t];
  float4 b = ((const float4*)x)[2 * t + 1];
  ushort u[8] = {f2bf(a.x), f2bf(a.y), f2bf(a.z), f2bf(a.w),
                 f2bf(b.x), f2bf(b.y), f2bf(b.z), f2bf(b.w)};
  ((uint4*)xh)[t] = *(const uint4*)u;
}

// Pack Wcat=[W_l;W_r] (256x128) into MFMA B-fragment order:
// Bp[((Cb*8+kb)*64+lane)*8 + j] = Wcat[kb*32+(lane>>4)*8+j][Cb*16+(lane&15)]
__global__ __launch_bounds__(256) void pack_kernel(const float* __restrict__ W_l,
                                                   const float* __restrict__ W_r,
                                                   ushort* __restrict__ Bp) {
  int t = blockIdx.x * 256 + threadIdx.x;  // t < 8*8*64
  int Cb = t >> 9, kb = (t >> 6) & 7, lane = t & 63;
  int n = Cb * 16 + (lane & 15);
  int k0 = kb * 32 + (lane >> 4) * 8;
  ushort u[8];
#pragma unroll
  for (int j = 0; j < 8; ++j) {
    int k = k0 + j;
    float w = (k < C) ? W_l[k * C + n] : W_r[(k - C) * C + n];
    u[j] = f2bf(w);
  }
  ((uint4*)Bp)[t] = *(const uint4*)u;
}

__global__ __launch_bounds__(256) void hist_kernel(const int* __restrict__ erow,
                                                   int* __restrict__ deg) {
  int t = blockIdx.x * 256 + threadIdx.x;
  if (t < E_EDGES / 4) {
    int4 r = ((const int4*)erow)[t];
    atomicAdd(&deg[r.x], 1);
    atomicAdd(&deg[r.y], 1);
    atomicAdd(&deg[r.z], 1);
    atomicAdd(&deg[r.w], 1);
  }
}

// 3-step scan: s1 per-1024-chunk sums, s2 scan of 98 chunk sums, s3 expand.
__global__ __launch_bounds__(256) void scan1_kernel(const int* __restrict__ deg,
                                                    int* __restrict__ psum) {
  __shared__ int l[256];
  int t = threadIdx.x;
  int i4 = blockIdx.x * 256 + t;
  int s = 0;
  if (i4 < N_NODES / 4) {
    int4 d = ((const int4*)deg)[i4];
    s = d.x + d.y + d.z + d.w;
  }
  l[t] = s;
  __syncthreads();
  for (int d = 128; d > 0; d >>= 1) {
    if (t < d) l[t] += l[t + d];
    __syncthreads();
  }
  if (t == 0) psum[blockIdx.x] = l[0];
}

__global__ __launch_bounds__(128) void scan2_kernel(const int* __restrict__ psum,
                                                    int* __restrict__ coff,
                                                    int* __restrict__ off) {
  __shared__ int l[128];
  const int NB = (N_NODES + 1023) / 1024;  // 98
  int t = threadIdx.x;
  int v = (t < NB) ? psum[t] : 0;
  l[t] = v;
  __syncthreads();
  for (int d = 1; d < 128; d <<= 1) {
    int u = (t >= d) ? l[t - d] : 0;
    __syncthreads();
    l[t] += u;
    __syncthreads();
  }
  if (t < NB) coff[t] = l[t] - v;          // exclusive chunk offset
  if (t == 127) off[N_NODES] = l[127];     // total == E
}

__global__ __launch_bounds__(256) void scan3_kernel(const int* __restrict__ deg,
                                                    const int* __restrict__ coff,
                                                    int* __restrict__ off,
                                                    int* __restrict__ cursor) {
  __shared__ int l[256];
  int t = threadIdx.x;
  int i4 = blockIdx.x * 256 + t;
  int g0 = 0, g1 = 0, g2 = 0, g3 = 0;
  bool ok = (i4 < N_NODES / 4);
  if (ok) {
    int4 d = ((const int4*)deg)[i4];
    g0 = d.x; g1 = d.y; g2 = d.z; g3 = d.w;
  }
  int s = g0 + g1 + g2 + g3;
  l[t] = s;
  __syncthreads();
  for (int d = 1; d < 256; d <<= 1) {
    int u = (t >= d) ? l[t - d] : 0;
    __syncthreads();
    l[t] += u;
    __syncthreads();
  }
  if (ok) {
    int p = coff[blockIdx.x] + l[t] - s;  // exclusive offset of this thread
    int i = i4 * 4;
    off[i] = p; cursor[i] = p; p += g0;
    off[i + 1] = p; cursor[i + 1] = p; p += g1;
    off[i + 2] = p; cursor[i + 2] = p; p += g2;
    off[i + 3] = p; cursor[i + 3] = p;
  }
}

__global__ __launch_bounds__(256) void build_kernel(
    const int* __restrict__ erow, const int* __restrict__ ecol,
    int* __restrict__ cursor, int* __restrict__ ssrc) {
  int t = blockIdx.x * 256 + threadIdx.x;
  if (t < E_EDGES / 4) {
    int4 r = ((const int4*)erow)[t];
    int4 c = ((const int4*)ecol)[t];
    ssrc[atomicAdd(&cursor[r.x], 1)] = c.x;
    ssrc[atomicAdd(&cursor[r.y], 1)] = c.y;
    ssrc[atomicAdd(&cursor[r.z], 1)] = c.z;
    ssrc[atomicAdd(&cursor[r.w], 1)] = c.w;
  }
}

// ---------------------------------------------------------------------------
// Fused gather-mean + MFMA GEMM:  out = relu([agg|x] @ [W_l;W_r] + b_l)
// 32 nodes/block. LDS A-tile: 32 x 264 bf16 (cols 0-127 agg, 128-255 own x,
// 8 pad -> row stride 528 B = 33*16, so b128 accesses stay 16B-aligned).
// MFMA 16x16x32_bf16: A[m=lane&15][k=(lane>>4)*8+j] from LDS ds_read_b128;
// B frags from pre-packed Bp (coalesced dwordx4, L2-resident);
// D[row=(lane>>4)*4+r][col=lane&15].
// ---------------------------------------------------------------------------
__global__ __launch_bounds__(256) void fused_kernel(
    const ushort* __restrict__ xh, const int* __restrict__ off,
    const int* __restrict__ ssrc, const ushort* __restrict__ Bp,
    const float* __restrict__ b_l, float* __restrict__ out) {
  __shared__ ushort lA[32][264];
  int tid = threadIdx.x;
  int lane = tid & 63;
  int wave = tid >> 6;
  long base = (long)blockIdx.x * 32;

  // Stage this block's own 32 bf16 x-rows into cols [128,256).
  // 32 rows x 16 uint4 per row (128 ushorts) = 512 uint4; 2 per thread.
  // (R3 bug: only 8 uint4/row were staged -> cols [192,256) were garbage.)
  for (int i = tid; i < 32 * 16; i += 256) {
    int r = i >> 4, q = i & 15;
    uint4 v = ((const uint4*)(xh + (base + r) * C))[q];
    *(uint4*)&lA[r][128 + q * 8] = v;
  }

  // Gather-mean into cols [0,128). Wave handles 8 nodes; lane owns ch pair.
  for (int j = 0; j < 8; ++j) {
    int n = wave * 8 + j;
    long row = base + n;
    int e0 = off[row];          // wave-uniform -> scalar
    int e1 = off[row + 1];
    float s0 = 0.0f, s1 = 0.0f;
    int e = e0;
    for (; e + 3 < e1; e += 4) {  // 4 row-loads in flight
      int sa = ssrc[e], sb = ssrc[e + 1], sc = ssrc[e + 2], sd = ssrc[e + 3];
      unsigned int va = ((const unsigned int*)(xh + (long)sa * C))[lane];
      unsigned int vb = ((const unsigned int*)(xh + (long)sb * C))[lane];
      unsigned int vc = ((const unsigned int*)(xh + (long)sc * C))[lane];
      unsigned int vd = ((const unsigned int*)(xh + (long)sd * C))[lane];
      s0 += bflo(va) + bflo(vb) + bflo(vc) + bflo(vd);
      s1 += bfhi(va) + bfhi(vb) + bfhi(vc) + bfhi(vd);
    }
    for (; e < e1; ++e) {
      unsigned int v = ((const unsigned int*)(xh + (long)ssrc[e] * C))[lane];
      s0 += bflo(v);
      s1 += bfhi(v);
    }
    float inv = 1.0f / fmaxf((float)(e1 - e0), 1.0f);
    unsigned int p = (unsigned int)f2bf(s0 * inv) |
                     ((unsigned int)f2bf(s1 * inv) << 16);
    *(unsigned int*)&lA[n][2 * lane] = p;
  }
  __syncthreads();

  // MFMA: wave w owns col-tiles Cb in {2w, 2w+1}, row-tiles R in {0,1}.
  f32x4 acc0 = {0, 0, 0, 0}, acc1 = {0, 0, 0, 0};
  f32x4 acc2 = {0, 0, 0, 0}, acc3 = {0, 0, 0, 0};
  int m = lane & 15, quad = lane >> 4;
  const ushort* bp0 = Bp + (((2 * wave + 0) * 8) * 64 + lane) * 8;
  const ushort* bp1 = Bp + (((2 * wave + 1) * 8) * 64 + lane) * 8;
#pragma unroll
  for (int kb = 0; kb < 8; ++kb) {
    short8 a0 = *(const short8*)&lA[m][kb * 32 + quad * 8];
    short8 a1 = *(const short8*)&lA[16 + m][kb * 32 + quad * 8];
    short8 b0 = *(const short8*)(bp0 + kb * 64 * 8);
    short8 b1 = *(const short8*)(bp1 + kb * 64 * 8);
    acc0 = __builtin_amdgcn_mfma_f32_16x16x32_bf16(a0, b0, acc0, 0, 0, 0);
    acc1 = __builtin_amdgcn_mfma_f32_16x16x32_bf16(a0, b1, acc1, 0, 0, 0);
    acc2 = __builtin_amdgcn_mfma_f32_16x16x32_bf16(a1, b0, acc2, 0, 0, 0);
    acc3 = __builtin_amdgcn_mfma_f32_16x16x32_bf16(a1, b1, acc3, 0, 0, 0);
  }

  int col0 = (2 * wave + 0) * 16 + m;
  int col1 = col0 + 16;
  float bl0 = b_l[col0], bl1 = b_l[col1];
#pragma unroll
  for (int r = 0; r < 4; ++r) {
    long row0 = base + quad * 4 + r;
    long row1 = row0 + 16;
    out[row0 * C + col0] = fmaxf(acc0[r] + bl0, 0.0f);
    out[row0 * C + col1] = fmaxf(acc1[r] + bl1, 0.0f);
    out[row1 * C + col0] = fmaxf(acc2[r] + bl0, 0.0f);
    out[row1 * C + col1] = fmaxf(acc3[r] + bl1, 0.0f);
  }
}

extern "C" void kernel_launch(void* const* d_in, const int* in_sizes, int n_in,
                              void* d_out, int out_size, void* d_ws, size_t ws_size,
                              hipStream_t stream) {
  const float* x   = (const float*)d_in[0];
  const int* erow  = (const int*)d_in[1];   // dst
  const int* ecol  = (const int*)d_in[2];   // src
  const float* W_l = (const float*)d_in[3];
  const float* b_l = (const float*)d_in[4];
  const float* W_r = (const float*)d_in[5];
  float* out = (float*)d_out;

  // ws layout (all 16B-aligned segments):
  char* p = (char*)d_ws;
  ushort* xh  = (ushort*)p;            p += (size_t)N_NODES * C * 2;  // 25.6MB
  ushort* Bp  = (ushort*)p;            p += 2 * C * C * 2;            // 64KB
  int* deg    = (int*)p;               p += (size_t)N_NODES * 4;
  int* off    = (int*)p;               p += (size_t)(N_NODES + 4) * 4;
  int* cursor = (int*)p;               p += (size_t)N_NODES * 4;
  int* ssrc   = (int*)p;               p += (size_t)E_EDGES * 4;
  int* psum   = (int*)p;               p += 128 * 4;
  int* coff   = (int*)p;

  const int NB_SCAN = (N_NODES + 1023) / 1024;  // 98

  hipMemsetAsync(deg, 0, N_NODES * sizeof(int), stream);
  cvt_kernel<<<N_NODES * C / 8 / 256, 256, 0, stream>>>(x, xh);
  pack_kernel<<<(8 * 8 * 64) / 256, 256, 0, stream>>>(W_l, W_r, Bp);
  hist_kernel<<<(E_EDGES / 4 + 255) / 256, 256, 0, stream>>>(erow, deg);
  scan1_kernel<<<NB_SCAN, 256, 0, stream>>>(deg, psum);
  scan2_kernel<<<1, 128, 0, stream>>>(psum, coff, off);
  scan3_kernel<<<NB_SCAN, 256, 0, stream>>>(deg, coff, off, cursor);
  build_kernel<<<(E_EDGES / 4 + 255) / 256, 256, 0, stream>>>(erow, ecol,
                                                              cursor, ssrc);
  fused_kernel<<<N_NODES / 32, 256, 0, stream>>>(xh, off, ssrc, Bp, b_l, out);
}

// Round 5
// 336.892 us; speedup vs baseline: 9.0117x; 1.1566x over previous
//
#include <hip/hip_runtime.h>

#define N_NODES 100000
#define E_EDGES 1600000
#define C 128
#define BSHIFT 10
#define NBKT 98   // ceil(N / 1024); bucket b covers nodes [b*1024, b*1024+1024)

typedef __attribute__((ext_vector_type(8))) short short8;   // 8 bf16 (4 VGPRs)
typedef __attribute__((ext_vector_type(4))) float f32x4;    // MFMA acc

__device__ __forceinline__ unsigned short f2bf(float f) {  // RNE fp32->bf16
  unsigned int b = __float_as_uint(f);
  return (unsigned short)((b + 0x7fffu + ((b >> 16) & 1u)) >> 16);
}
__device__ __forceinline__ float bflo(unsigned int v) {
  return __uint_as_float(v << 16);
}
__device__ __forceinline__ float bfhi(unsigned int v) {
  return __uint_as_float(v & 0xffff0000u);
}

// x (fp32) -> xh (bf16). 77 MB streaming pass.
__global__ __launch_bounds__(256) void cvt_kernel(const float* __restrict__ x,
                                                  ushort* __restrict__ xh) {
  int t = blockIdx.x * 256 + threadIdx.x;  // t < N*C/8
  float4 a = ((const float4*)x)[2 * t];
  float4 b = ((const float4*)x)[2 * t + 1];
  ushort u[8] = {f2bf(a.x), f2bf(a.y), f2bf(a.z), f2bf(a.w),
                 f2bf(b.x), f2bf(b.y), f2bf(b.z), f2bf(b.w)};
  ((uint4*)xh)[t] = *(const uint4*)u;
}

// Pack Wcat=[W_l;W_r] (256x128) into MFMA B-fragment order:
// Bp[((Cb*8+kb)*64+lane)*8 + j] = Wcat[kb*32+(lane>>4)*8+j][Cb*16+(lane&15)]
__global__ __launch_bounds__(256) void pack_kernel(const float* __restrict__ W_l,
                                                   const float* __restrict__ W_r,
                                                   ushort* __restrict__ Bp) {
  int t = blockIdx.x * 256 + threadIdx.x;  // t < 8*8*64
  int Cb = t >> 9, kb = (t >> 6) & 7, lane = t & 63;
  int n = Cb * 16 + (lane & 15);
  int k0 = kb * 32 + (lane >> 4) * 8;
  ushort u[8];
#pragma unroll
  for (int j = 0; j < 8; ++j) {
    int k = k0 + j;
    float w = (k < C) ? W_l[k * C + n] : W_r[(k - C) * C + n];
    u[j] = f2bf(w);
  }
  ((uint4*)Bp)[t] = *(const uint4*)u;
}

__global__ __launch_bounds__(256) void hist_kernel(const int* __restrict__ erow,
                                                   int* __restrict__ deg) {
  int t = blockIdx.x * 256 + threadIdx.x;
  if (t < E_EDGES / 4) {
    int4 r = ((const int4*)erow)[t];
    atomicAdd(&deg[r.x], 1);
    atomicAdd(&deg[r.y], 1);
    atomicAdd(&deg[r.z], 1);
    atomicAdd(&deg[r.w], 1);
  }
}

// 3-step scan: s1 per-1024-chunk sums, s2 scan of 98 chunk sums, s3 expand.
__global__ __launch_bounds__(256) void scan1_kernel(const int* __restrict__ deg,
                                                    int* __restrict__ psum) {
  __shared__ int l[256];
  int t = threadIdx.x;
  int i4 = blockIdx.x * 256 + t;
  int s = 0;
  if (i4 < N_NODES / 4) {
    int4 d = ((const int4*)deg)[i4];
    s = d.x + d.y + d.z + d.w;
  }
  l[t] = s;
  __syncthreads();
  for (int d = 128; d > 0; d >>= 1) {
    if (t < d) l[t] += l[t + d];
    __syncthreads();
  }
  if (t == 0) psum[blockIdx.x] = l[0];
}

__global__ __launch_bounds__(128) void scan2_kernel(const int* __restrict__ psum,
                                                    int* __restrict__ coff,
                                                    int* __restrict__ off) {
  __shared__ int l[128];
  const int NB = (N_NODES + 1023) / 1024;  // 98
  int t = threadIdx.x;
  int v = (t < NB) ? psum[t] : 0;
  l[t] = v;
  __syncthreads();
  for (int d = 1; d < 128; d <<= 1) {
    int u = (t >= d) ? l[t - d] : 0;
    __syncthreads();
    l[t] += u;
    __syncthreads();
  }
  if (t < NB) coff[t] = l[t] - v;          // exclusive chunk offset
  if (t == 127) off[N_NODES] = l[127];     // total == E
}

// Also emits bcur[b] = off[b*1024] (bucket-region base for passA chunk alloc).
__global__ __launch_bounds__(256) void scan3_kernel(const int* __restrict__ deg,
                                                    const int* __restrict__ coff,
                                                    int* __restrict__ off,
                                                    int* __restrict__ bcur) {
  __shared__ int l[256];
  int t = threadIdx.x;
  int i4 = blockIdx.x * 256 + t;
  int g0 = 0, g1 = 0, g2 = 0, g3 = 0;
  bool ok = (i4 < N_NODES / 4);
  if (ok) {
    int4 d = ((const int4*)deg)[i4];
    g0 = d.x; g1 = d.y; g2 = d.z; g3 = d.w;
  }
  int s = g0 + g1 + g2 + g3;
  l[t] = s;
  __syncthreads();
  for (int d = 1; d < 256; d <<= 1) {
    int u = (t >= d) ? l[t - d] : 0;
    __syncthreads();
    l[t] += u;
    __syncthreads();
  }
  if (ok) {
    int p = coff[blockIdx.x] + l[t] - s;  // exclusive offset of this thread
    int i = i4 * 4;
    if ((i & 1023) == 0) bcur[i >> BSHIFT] = p;  // bucket base (i mult of 4)
    off[i] = p; p += g0;
    off[i + 1] = p; p += g1;
    off[i + 2] = p; p += g2;
    off[i + 3] = p;
  }
}

// ---------------------------------------------------------------------------
// passA: bucketed multisplit of edges by dst>>10. Each block (1024 edges)
// LDS-splits into 98 buckets, chunk-allocates per bucket via ONE global
// atomic, and writes (src,dst) pairs in bucket-ordered contiguous runs
// (~10 pairs = 84 B per run -> near-full-line writes, no 17x amplification).
// Bucket regions in `pairs` mirror CSR off[] ranges exactly.
// ---------------------------------------------------------------------------
__global__ __launch_bounds__(256) void passA_kernel(
    const int* __restrict__ erow, const int* __restrict__ ecol,
    int* __restrict__ bcur, int2* __restrict__ pairs) {
  __shared__ int cnt[NBKT], pos[NBKT], loff[NBKT], total;
  __shared__ int2 lbuf[1024];
  __shared__ int gaddr[1024];
  int tid = threadIdx.x;
  int idx = blockIdx.x * 256 + tid;  // int4 index: edges [4*idx, 4*idx+4)
  for (int b = tid; b < NBKT; b += 256) cnt[b] = 0;
  __syncthreads();

  bool ok = (4 * idx < E_EDGES);
  int4 r, c;
  int bk[4], rk[4];
  if (ok) {
    r = ((const int4*)erow)[idx];
    c = ((const int4*)ecol)[idx];
    bk[0] = r.x >> BSHIFT; rk[0] = atomicAdd(&cnt[bk[0]], 1);
    bk[1] = r.y >> BSHIFT; rk[1] = atomicAdd(&cnt[bk[1]], 1);
    bk[2] = r.z >> BSHIFT; rk[2] = atomicAdd(&cnt[bk[2]], 1);
    bk[3] = r.w >> BSHIFT; rk[3] = atomicAdd(&cnt[bk[3]], 1);
  }
  __syncthreads();

  if (tid < NBKT) pos[tid] = atomicAdd(&bcur[tid], cnt[tid]);
  if (tid == 0) {
    int run = 0;
    for (int b = 0; b < NBKT; ++b) { loff[b] = run; run += cnt[b]; }
    total = run;
  }
  __syncthreads();

  if (ok) {
    int s0 = loff[bk[0]] + rk[0];
    lbuf[s0] = make_int2(c.x, r.x); gaddr[s0] = pos[bk[0]] + rk[0];
    int s1 = loff[bk[1]] + rk[1];
    lbuf[s1] = make_int2(c.y, r.y); gaddr[s1] = pos[bk[1]] + rk[1];
    int s2 = loff[bk[2]] + rk[2];
    lbuf[s2] = make_int2(c.z, r.z); gaddr[s2] = pos[bk[2]] + rk[2];
    int s3 = loff[bk[3]] + rk[3];
    lbuf[s3] = make_int2(c.w, r.w); gaddr[s3] = pos[bk[3]] + rk[3];
  }
  __syncthreads();

  int tot = total;
  for (int i = tid; i < tot; i += 256)
    pairs[gaddr[i]] = lbuf[i];  // bucket-ordered runs -> coalesced
}

// ---------------------------------------------------------------------------
// passB: one block per bucket. CSR cursors for the bucket's 1024 nodes in
// LDS; scattered ssrc writes confined to this bucket's private ~64 KB CSR
// window (single writer, L2-resident, fully covered -> clean write-back).
// ---------------------------------------------------------------------------
__global__ __launch_bounds__(1024) void passB_kernel(
    const int2* __restrict__ pairs, const int* __restrict__ off,
    int* __restrict__ ssrc) {
  __shared__ int cur[1024];
  int b = blockIdx.x;
  int nbase = b << BSHIFT;
  int nn = min(1024, N_NODES - nbase);
  int t = threadIdx.x;
  if (t < nn) cur[t] = off[nbase + t];
  __syncthreads();
  int estart = off[nbase];
  int hi = min(nbase + 1024, N_NODES);
  int eend = off[hi];
  for (int e = estart + t; e < eend; e += 1024) {
    int2 p = pairs[e];
    int pos = atomicAdd(&cur[p.y - nbase], 1);
    ssrc[pos] = p.x;
  }
}

// ---------------------------------------------------------------------------
// Fused gather-mean + MFMA GEMM:  out = relu([agg|x] @ [W_l;W_r] + b_l)
// (unchanged from R4 — passed with absmax 0.031)
// ---------------------------------------------------------------------------
__global__ __launch_bounds__(256) void fused_kernel(
    const ushort* __restrict__ xh, const int* __restrict__ off,
    const int* __restrict__ ssrc, const ushort* __restrict__ Bp,
    const float* __restrict__ b_l, float* __restrict__ out) {
  __shared__ ushort lA[32][264];
  int tid = threadIdx.x;
  int lane = tid & 63;
  int wave = tid >> 6;
  long base = (long)blockIdx.x * 32;

  // Stage this block's own 32 bf16 x-rows into cols [128,256).
  for (int i = tid; i < 32 * 16; i += 256) {
    int r = i >> 4, q = i & 15;
    uint4 v = ((const uint4*)(xh + (base + r) * C))[q];
    *(uint4*)&lA[r][128 + q * 8] = v;
  }

  // Gather-mean into cols [0,128). Wave handles 8 nodes; lane owns ch pair.
  for (int j = 0; j < 8; ++j) {
    int n = wave * 8 + j;
    long row = base + n;
    int e0 = off[row];          // wave-uniform -> scalar
    int e1 = off[row + 1];
    float s0 = 0.0f, s1 = 0.0f;
    int e = e0;
    for (; e + 3 < e1; e += 4) {  // 4 row-loads in flight
      int sa = ssrc[e], sb = ssrc[e + 1], sc = ssrc[e + 2], sd = ssrc[e + 3];
      unsigned int va = ((const unsigned int*)(xh + (long)sa * C))[lane];
      unsigned int vb = ((const unsigned int*)(xh + (long)sb * C))[lane];
      unsigned int vc = ((const unsigned int*)(xh + (long)sc * C))[lane];
      unsigned int vd = ((const unsigned int*)(xh + (long)sd * C))[lane];
      s0 += bflo(va) + bflo(vb) + bflo(vc) + bflo(vd);
      s1 += bfhi(va) + bfhi(vb) + bfhi(vc) + bfhi(vd);
    }
    for (; e < e1; ++e) {
      unsigned int v = ((const unsigned int*)(xh + (long)ssrc[e] * C))[lane];
      s0 += bflo(v);
      s1 += bfhi(v);
    }
    float inv = 1.0f / fmaxf((float)(e1 - e0), 1.0f);
    unsigned int p = (unsigned int)f2bf(s0 * inv) |
                     ((unsigned int)f2bf(s1 * inv) << 16);
    *(unsigned int*)&lA[n][2 * lane] = p;
  }
  __syncthreads();

  // MFMA: wave w owns col-tiles Cb in {2w, 2w+1}, row-tiles R in {0,1}.
  f32x4 acc0 = {0, 0, 0, 0}, acc1 = {0, 0, 0, 0};
  f32x4 acc2 = {0, 0, 0, 0}, acc3 = {0, 0, 0, 0};
  int m = lane & 15, quad = lane >> 4;
  const ushort* bp0 = Bp + (((2 * wave + 0) * 8) * 64 + lane) * 8;
  const ushort* bp1 = Bp + (((2 * wave + 1) * 8) * 64 + lane) * 8;
#pragma unroll
  for (int kb = 0; kb < 8; ++kb) {
    short8 a0 = *(const short8*)&lA[m][kb * 32 + quad * 8];
    short8 a1 = *(const short8*)&lA[16 + m][kb * 32 + quad * 8];
    short8 b0 = *(const short8*)(bp0 + kb * 64 * 8);
    short8 b1 = *(const short8*)(bp1 + kb * 64 * 8);
    acc0 = __builtin_amdgcn_mfma_f32_16x16x32_bf16(a0, b0, acc0, 0, 0, 0);
    acc1 = __builtin_amdgcn_mfma_f32_16x16x32_bf16(a0, b1, acc1, 0, 0, 0);
    acc2 = __builtin_amdgcn_mfma_f32_16x16x32_bf16(a1, b0, acc2, 0, 0, 0);
    acc3 = __builtin_amdgcn_mfma_f32_16x16x32_bf16(a1, b1, acc3, 0, 0, 0);
  }

  int col0 = (2 * wave + 0) * 16 + m;
  int col1 = col0 + 16;
  float bl0 = b_l[col0], bl1 = b_l[col1];
#pragma unroll
  for (int r = 0; r < 4; ++r) {
    long row0 = base + quad * 4 + r;
    long row1 = row0 + 16;
    out[row0 * C + col0] = fmaxf(acc0[r] + bl0, 0.0f);
    out[row0 * C + col1] = fmaxf(acc1[r] + bl1, 0.0f);
    out[row1 * C + col0] = fmaxf(acc2[r] + bl0, 0.0f);
    out[row1 * C + col1] = fmaxf(acc3[r] + bl1, 0.0f);
  }
}

extern "C" void kernel_launch(void* const* d_in, const int* in_sizes, int n_in,
                              void* d_out, int out_size, void* d_ws, size_t ws_size,
                              hipStream_t stream) {
  const float* x   = (const float*)d_in[0];
  const int* erow  = (const int*)d_in[1];   // dst
  const int* ecol  = (const int*)d_in[2];   // src
  const float* W_l = (const float*)d_in[3];
  const float* b_l = (const float*)d_in[4];
  const float* W_r = (const float*)d_in[5];
  float* out = (float*)d_out;

  // ws layout (16B-aligned segments), ~45.7 MB total:
  char* p = (char*)d_ws;
  ushort* xh  = (ushort*)p;            p += (size_t)N_NODES * C * 2;  // 25.6MB
  ushort* Bp  = (ushort*)p;            p += 2 * C * C * 2;            // 64KB
  int* deg    = (int*)p;               p += (size_t)N_NODES * 4;
  int* off    = (int*)p;               p += (size_t)(N_NODES + 4) * 4;
  int2* pairs = (int2*)p;              p += (size_t)E_EDGES * 8;      // 12.8MB
  int* ssrc   = (int*)p;               p += (size_t)E_EDGES * 4;      // 6.4MB
  int* psum   = (int*)p;               p += 128 * 4;
  int* coff   = (int*)p;               p += 128 * 4;
  int* bcur   = (int*)p;

  const int NB_SCAN = (N_NODES + 1023) / 1024;  // 98

  hipMemsetAsync(deg, 0, N_NODES * sizeof(int), stream);
  cvt_kernel<<<N_NODES * C / 8 / 256, 256, 0, stream>>>(x, xh);
  pack_kernel<<<(8 * 8 * 64) / 256, 256, 0, stream>>>(W_l, W_r, Bp);
  hist_kernel<<<(E_EDGES / 4 + 255) / 256, 256, 0, stream>>>(erow, deg);
  scan1_kernel<<<NB_SCAN, 256, 0, stream>>>(deg, psum);
  scan2_kernel<<<1, 128, 0, stream>>>(psum, coff, off);
  scan3_kernel<<<NB_SCAN, 256, 0, stream>>>(deg, coff, off, bcur);
  passA_kernel<<<(E_EDGES / 4 + 255) / 256, 256, 0, stream>>>(erow, ecol, bcur,
                                                              pairs);
  passB_kernel<<<NBKT, 1024, 0, stream>>>(pairs, off, ssrc);
  fused_kernel<<<N_NODES / 32, 256, 0, stream>>>(xh, off, ssrc, Bp, b_l, out);
}

// Round 6
// 234.785 us; speedup vs baseline: 12.9308x; 1.4349x over previous
//
#include <hip/hip_runtime.h>

#define N_NODES 100000
#define E_EDGES 1600000
#define C 128
#define BSHIFT 10
#define NBKT 98       // ceil(N/1024)
#define CAP 18432     // bucket capacity; mean 16384, sigma ~127 -> +16 sigma

typedef __attribute__((ext_vector_type(8))) short short8;   // 8 bf16 (4 VGPRs)
typedef __attribute__((ext_vector_type(4))) float f32x4;    // MFMA acc

__device__ __forceinline__ unsigned short f2bf(float f) {  // RNE fp32->bf16
  unsigned int b = __float_as_uint(f);
  return (unsigned short)((b + 0x7fffu + ((b >> 16) & 1u)) >> 16);
}
__device__ __forceinline__ float bflo(unsigned int v) {
  return __uint_as_float(v << 16);
}
__device__ __forceinline__ float bfhi(unsigned int v) {
  return __uint_as_float(v & 0xffff0000u);
}

// x (fp32) -> xh (bf16). 77 MB streaming pass.
__global__ __launch_bounds__(256) void cvt_kernel(const float* __restrict__ x,
                                                  ushort* __restrict__ xh) {
  int t = blockIdx.x * 256 + threadIdx.x;  // t < N*C/8
  float4 a = ((const float4*)x)[2 * t];
  float4 b = ((const float4*)x)[2 * t + 1];
  ushort u[8] = {f2bf(a.x), f2bf(a.y), f2bf(a.z), f2bf(a.w),
                 f2bf(b.x), f2bf(b.y), f2bf(b.z), f2bf(b.w)};
  ((uint4*)xh)[t] = *(const uint4*)u;
}

// Pack Wcat=[W_l;W_r] (256x128) into MFMA B-fragment order.
__global__ __launch_bounds__(256) void pack_kernel(const float* __restrict__ W_l,
                                                   const float* __restrict__ W_r,
                                                   ushort* __restrict__ Bp) {
  int t = blockIdx.x * 256 + threadIdx.x;  // t < 8*8*64
  int Cb = t >> 9, kb = (t >> 6) & 7, lane = t & 63;
  int n = Cb * 16 + (lane & 15);
  int k0 = kb * 32 + (lane >> 4) * 8;
  ushort u[8];
#pragma unroll
  for (int j = 0; j < 8; ++j) {
    int k = k0 + j;
    float w = (k < C) ? W_l[k * C + n] : W_r[(k - C) * C + n];
    u[j] = f2bf(w);
  }
  ((uint4*)Bp)[t] = *(const uint4*)u;
}

// ---------------------------------------------------------------------------
// passA: multisplit edges by dst>>10 into fixed-capacity bucket regions of
// `pairs` (payload: src<<10 | dst&1023, one int per edge). 512 thr / 2048
// edges per block; LDS reorder so global writes are bucket-ordered ~21-pair
// (84 B) runs. No pre-scan needed (fixed CAP) -> hist/scan1/scan3 deleted.
// ---------------------------------------------------------------------------
__global__ __launch_bounds__(512) void passA_kernel(
    const int* __restrict__ erow, const int* __restrict__ ecol,
    int* __restrict__ bcnt, int* __restrict__ pairs) {
  __shared__ int cnt[NBKT], pos[NBKT], loff[NBKT], total;
  __shared__ int lbuf[2048];
  __shared__ int gaddr[2048];
  int tid = threadIdx.x;
  int idx = blockIdx.x * 512 + tid;  // int4 index: edges [4*idx, 4*idx+4)
  for (int b = tid; b < NBKT; b += 512) cnt[b] = 0;
  __syncthreads();

  bool ok = (idx < E_EDGES / 4);
  int4 r, c;
  int bk[4], rk[4];
  if (ok) {
    r = ((const int4*)erow)[idx];
    c = ((const int4*)ecol)[idx];
    bk[0] = r.x >> BSHIFT; rk[0] = atomicAdd(&cnt[bk[0]], 1);
    bk[1] = r.y >> BSHIFT; rk[1] = atomicAdd(&cnt[bk[1]], 1);
    bk[2] = r.z >> BSHIFT; rk[2] = atomicAdd(&cnt[bk[2]], 1);
    bk[3] = r.w >> BSHIFT; rk[3] = atomicAdd(&cnt[bk[3]], 1);
  }
  __syncthreads();

  if (tid < NBKT) pos[tid] = atomicAdd(&bcnt[tid], cnt[tid]);
  if (tid == 0) {
    int run = 0;
    for (int b = 0; b < NBKT; ++b) { loff[b] = run; run += cnt[b]; }
    total = run;
  }
  __syncthreads();

  if (ok) {
    int src[4] = {c.x, c.y, c.z, c.w};
    int dst[4] = {r.x, r.y, r.z, r.w};
#pragma unroll
    for (int i = 0; i < 4; ++i) {
      int s = loff[bk[i]] + rk[i];
      lbuf[s] = (src[i] << BSHIFT) | (dst[i] & (  (1<<BSHIFT) - 1));
      int g = pos[bk[i]] + rk[i];
      gaddr[s] = (g < CAP) ? bk[i] * CAP + g : -1;  // overflow guard (16 sigma)
    }
  }
  __syncthreads();

  int tot = total;
  for (int i = tid; i < tot; i += 512) {
    int g = gaddr[i];
    if (g >= 0) pairs[g] = lbuf[i];  // bucket-ordered runs -> coalesced
  }
}

// Exclusive scan of the 98 bucket counts -> global bucket bases.
__global__ __launch_bounds__(128) void bscan_kernel(const int* __restrict__ bcnt,
                                                    int* __restrict__ bbase) {
  __shared__ int l[128];
  int t = threadIdx.x;
  int v = (t < NBKT) ? min(bcnt[t], CAP) : 0;
  l[t] = v;
  __syncthreads();
  for (int d = 1; d < 128; d <<= 1) {
    int u = (t >= d) ? l[t - d] : 0;
    __syncthreads();
    l[t] += u;
    __syncthreads();
  }
  if (t < NBKT) bbase[t] = l[t] - v;
}

// ---------------------------------------------------------------------------
// passB: one block per bucket. LDS count of the bucket's 1024 local nodes,
// LDS scan -> writes off[] (coalesced) AND scatters ssrc into the bucket's
// private ~64 KB window (single writer, L2-resident, fully covered).
// ---------------------------------------------------------------------------
__global__ __launch_bounds__(1024) void passB_kernel(
    const int* __restrict__ pairs, const int* __restrict__ bcnt,
    const int* __restrict__ bbase, int* __restrict__ off,
    int* __restrict__ ssrc) {
  __shared__ int l[1024];
  __shared__ int cur[1024];
  int b = blockIdx.x, t = threadIdx.x;
  int nbase = b << BSHIFT;
  int nn = min(1024, N_NODES - nbase);
  int cnt = min(bcnt[b], CAP);
  int gbase = bbase[b];
  const int* bp = pairs + b * CAP;

  l[t] = 0;
  __syncthreads();
  for (int e = t; e < cnt; e += 1024) atomicAdd(&l[bp[e] & 1023], 1);
  __syncthreads();
  int own = l[t];
  for (int d = 1; d < 1024; d <<= 1) {  // inclusive Hillis-Steele
    int u = (t >= d) ? l[t - d] : 0;
    __syncthreads();
    l[t] += u;
    __syncthreads();
  }
  int excl = l[t] - own;
  if (t < nn) { off[nbase + t] = gbase + excl; cur[t] = excl; }
  if (b == NBKT - 1 && t == 1023) off[N_NODES] = gbase + l[1023];
  __syncthreads();
  for (int e = t; e < cnt; e += 1024) {
    int p = bp[e];
    int pos = atomicAdd(&cur[p & 1023], 1);
    ssrc[gbase + pos] = p >> BSHIFT;
  }
}

// ---------------------------------------------------------------------------
// Fused gather-mean + MFMA GEMM:  out = relu([agg|x] @ [W_l;W_r] + b_l)
// Gather re-vectorized: quarter-wave per edge-row (16 lanes x uint4 = 8 ch),
// 4 edges per load instruction, 2-deep unroll (8 edges in flight / wave),
// cross-quarter shfl_xor(16|32) reduction per node.
// ---------------------------------------------------------------------------
__global__ __launch_bounds__(256) void fused_kernel(
    const ushort* __restrict__ xh, const int* __restrict__ off,
    const int* __restrict__ ssrc, const ushort* __restrict__ Bp,
    const float* __restrict__ b_l, float* __restrict__ out) {
  __shared__ ushort lA[32][264];
  int tid = threadIdx.x;
  int lane = tid & 63;
  int wave = tid >> 6;
  long base = (long)blockIdx.x * 32;

  // Stage this block's own 32 bf16 x-rows into cols [128,256).
  for (int i = tid; i < 32 * 16; i += 256) {
    int r = i >> 4, q = i & 15;
    uint4 v = ((const uint4*)(xh + (base + r) * C))[q];
    *(uint4*)&lA[r][128 + q * 8] = v;
  }

  int l4 = lane & 15;   // channel group: ch [l4*8, l4*8+8)
  int q = lane >> 4;    // quarter: edge stripe

  for (int j = 0; j < 8; ++j) {
    int n = wave * 8 + j;
    long row = base + n;
    int e0 = off[row];
    int e1 = off[row + 1];
    float s[8];
#pragma unroll
    for (int i = 0; i < 8; ++i) s[i] = 0.0f;

    int e = e0 + q;
    for (; e + 4 < e1; e += 8) {  // 2 uint4 loads in flight per lane
      int sa = ssrc[e];
      int sb = ssrc[e + 4];
      uint4 va = ((const uint4*)(xh + (long)sa * C))[l4];
      uint4 vb = ((const uint4*)(xh + (long)sb * C))[l4];
      s[0] += bflo(va.x) + bflo(vb.x); s[1] += bfhi(va.x) + bfhi(vb.x);
      s[2] += bflo(va.y) + bflo(vb.y); s[3] += bfhi(va.y) + bfhi(vb.y);
      s[4] += bflo(va.z) + bflo(vb.z); s[5] += bfhi(va.z) + bfhi(vb.z);
      s[6] += bflo(va.w) + bflo(vb.w); s[7] += bfhi(va.w) + bfhi(vb.w);
    }
    if (e < e1) {  // tail: at most one more stripe element
      int sa = ssrc[e];
      uint4 va = ((const uint4*)(xh + (long)sa * C))[l4];
      s[0] += bflo(va.x); s[1] += bfhi(va.x);
      s[2] += bflo(va.y); s[3] += bfhi(va.y);
      s[4] += bflo(va.z); s[5] += bfhi(va.z);
      s[6] += bflo(va.w); s[7] += bfhi(va.w);
    }
#pragma unroll
    for (int i = 0; i < 8; ++i) {
      s[i] += __shfl_xor(s[i], 16);
      s[i] += __shfl_xor(s[i], 32);
    }
    float inv = 1.0f / fmaxf((float)(e1 - e0), 1.0f);
    if (q == 0) {
      ushort u[8];
#pragma unroll
      for (int i = 0; i < 8; ++i) u[i] = f2bf(s[i] * inv);
      *(uint4*)&lA[n][l4 * 8] = *(const uint4*)u;
    }
  }
  __syncthreads();

  // MFMA: wave w owns col-tiles Cb in {2w, 2w+1}, row-tiles R in {0,1}.
  f32x4 acc0 = {0, 0, 0, 0}, acc1 = {0, 0, 0, 0};
  f32x4 acc2 = {0, 0, 0, 0}, acc3 = {0, 0, 0, 0};
  int m = lane & 15, quad = lane >> 4;
  const ushort* bp0 = Bp + (((2 * wave + 0) * 8) * 64 + lane) * 8;
  const ushort* bp1 = Bp + (((2 * wave + 1) * 8) * 64 + lane) * 8;
#pragma unroll
  for (int kb = 0; kb < 8; ++kb) {
    short8 a0 = *(const short8*)&lA[m][kb * 32 + quad * 8];
    short8 a1 = *(const short8*)&lA[16 + m][kb * 32 + quad * 8];
    short8 b0 = *(const short8*)(bp0 + kb * 64 * 8);
    short8 b1 = *(const short8*)(bp1 + kb * 64 * 8);
    acc0 = __builtin_amdgcn_mfma_f32_16x16x32_bf16(a0, b0, acc0, 0, 0, 0);
    acc1 = __builtin_amdgcn_mfma_f32_16x16x32_bf16(a0, b1, acc1, 0, 0, 0);
    acc2 = __builtin_amdgcn_mfma_f32_16x16x32_bf16(a1, b0, acc2, 0, 0, 0);
    acc3 = __builtin_amdgcn_mfma_f32_16x16x32_bf16(a1, b1, acc3, 0, 0, 0);
  }

  int col0 = (2 * wave + 0) * 16 + m;
  int col1 = col0 + 16;
  float bl0 = b_l[col0], bl1 = b_l[col1];
#pragma unroll
  for (int r = 0; r < 4; ++r) {
    long row0 = base + quad * 4 + r;
    long row1 = row0 + 16;
    out[row0 * C + col0] = fmaxf(acc0[r] + bl0, 0.0f);
    out[row0 * C + col1] = fmaxf(acc1[r] + bl1, 0.0f);
    out[row1 * C + col0] = fmaxf(acc2[r] + bl0, 0.0f);
    out[row1 * C + col1] = fmaxf(acc3[r] + bl1, 0.0f);
  }
}

extern "C" void kernel_launch(void* const* d_in, const int* in_sizes, int n_in,
                              void* d_out, int out_size, void* d_ws, size_t ws_size,
                              hipStream_t stream) {
  const float* x   = (const float*)d_in[0];
  const int* erow  = (const int*)d_in[1];   // dst
  const int* ecol  = (const int*)d_in[2];   // src
  const float* W_l = (const float*)d_in[3];
  const float* b_l = (const float*)d_in[4];
  const float* W_r = (const float*)d_in[5];
  float* out = (float*)d_out;

  // ws layout (16B-aligned segments), ~40 MB total:
  char* p = (char*)d_ws;
  ushort* xh  = (ushort*)p;  p += (size_t)N_NODES * C * 2;      // 25.6 MB
  ushort* Bp  = (ushort*)p;  p += 2 * C * C * 2;                // 64 KB
  int* off    = (int*)p;     p += (size_t)(N_NODES + 4) * 4;    // 400 KB
  int* pairs  = (int*)p;     p += (size_t)NBKT * CAP * 4;       // 7.2 MB
  int* ssrc   = (int*)p;     p += (size_t)E_EDGES * 4;          // 6.4 MB
  int* bcnt   = (int*)p;     p += 128 * 4;
  int* bbase  = (int*)p;

  hipMemsetAsync(bcnt, 0, NBKT * sizeof(int), stream);
  cvt_kernel<<<N_NODES * C / 8 / 256, 256, 0, stream>>>(x, xh);
  pack_kernel<<<(8 * 8 * 64) / 256, 256, 0, stream>>>(W_l, W_r, Bp);
  passA_kernel<<<(E_EDGES / 4 + 511) / 512, 512, 0, stream>>>(erow, ecol, bcnt,
                                                              pairs);
  bscan_kernel<<<1, 128, 0, stream>>>(bcnt, bbase);
  passB_kernel<<<NBKT, 1024, 0, stream>>>(pairs, bcnt, bbase, off, ssrc);
  fused_kernel<<<N_NODES / 32, 256, 0, stream>>>(xh, off, ssrc, Bp, b_l, out);
}